// Round 9
// baseline (149.543 us; speedup 1.0000x reference)
//
#include <hip/hip_runtime.h>
#include <hip/hip_bf16.h>
#include <stdint.h>

#define B_ 4
#define S_ 1024
#define D_ 1024
#define E_ 8
#define DE_ 128
#define SCALE_ 0.03125f   // 1/sqrt(1024)

typedef __attribute__((ext_vector_type(8))) short short8;
typedef __attribute__((ext_vector_type(4))) float f32x4;
typedef unsigned short ushort_t;
typedef unsigned int uint32;

__device__ __forceinline__ ushort_t f2bf(float f) {
    uint32 u = __float_as_uint(f);
    uint32 r = u + 0x7fffu + ((u >> 16) & 1u);   // round-to-nearest-even
    return (ushort_t)(r >> 16);
}

// Async global->LDS DMA, 16B/lane. LDS dst = wave-uniform base + lane*16.
#define GLOAD_LDS16(g, l) __builtin_amdgcn_global_load_lds( \
    (const __attribute__((address_space(1))) unsigned int*)(g), \
    (__attribute__((address_space(3))) unsigned int*)(l), 16, 0, 0)

// Stage a 64-row x 128-bf16 tile (16 KB), XOR-swizzled 16B-chunk order.
__device__ __forceinline__ void stage64(const ushort_t* __restrict__ g,
                                        size_t stride, ushort_t* lds,
                                        int w, int lane) {
    #pragma unroll
    for (int j = 0; j < 4; ++j) {
        int cb = (w * 4 + j) << 6;
        int ch = cb + lane;
        int r = ch >> 4, c = ch & 15;
        GLOAD_LDS16(g + (size_t)r * stride + ((c ^ (r & 7)) << 3),
                    lds + ((size_t)cb << 3));
    }
}
// 128-row x 128-bf16 tile (32 KB).
__device__ __forceinline__ void stage128(const ushort_t* __restrict__ g,
                                         size_t stride, ushort_t* lds,
                                         int w, int lane) {
    #pragma unroll
    for (int j = 0; j < 8; ++j) {
        int cb = (w * 8 + j) << 6;
        int ch = cb + lane;
        int r = ch >> 4, c = ch & 15;
        GLOAD_LDS16(g + (size_t)r * stride + ((c ^ (r & 7)) << 3),
                    lds + ((size_t)cb << 3));
    }
}
// Read one MFMA frag (16B) from a swizzled tile (row-major, 16 chunks/row).
__device__ __forceinline__ short8 fld(const ushort_t* lds, int row, int c) {
    return *(const short8*)(lds + (((row << 4) + (c ^ (row & 7))) << 3));
}

__device__ __forceinline__ void top2(const float* rp, int& i1, int& i2) {
    float v1 = rp[0]; i1 = 0;
    #pragma unroll
    for (int i = 1; i < 8; ++i) { float v = rp[i]; if (v > v1) { v1 = v; i1 = i; } }
    float v2 = -1e30f; i2 = 0;
    #pragma unroll
    for (int i = 0; i < 8; ++i) {
        if (i == i1) continue;
        float v = rp[i]; if (v > v2) { v2 = v; i2 = i; }
    }
}

// ---------------------------------------------------------------------------
// Kernel 1: prep. Q,K fp32 -> bf16 [B][E][S][DE] (em-active planes only);
// V fp32 -> bf16 transposed Vt [B][E][DE][S] (top-2 planes only).
// ---------------------------------------------------------------------------
__global__ __launch_bounds__(256) void prep_kernel(
        const float* __restrict__ Q, const float* __restrict__ K,
        const float* __restrict__ V, const float* __restrict__ route,
        const int* __restrict__ em,
        ushort_t* __restrict__ Qb, ushort_t* __restrict__ Kb,
        ushort_t* __restrict__ Vt) {
    __shared__ ushort_t tile[64][130];
    const int tid = threadIdx.x;
    const int sc = blockIdx.x, e = blockIdx.y, b = blockIdx.z;
    const int s0 = sc * 64;
    const size_t plane = ((size_t)(b * 8 + e)) << 17;

    const bool ak = em[e * B_ + b] != 0;
    int i1, i2; top2(route + b * 8, i1, i2);
    const bool av = (e == i1) || (e == i2);
    if (!ak && !av) return;

    if (ak) {
        #pragma unroll
        for (int i = 0; i < 8; ++i) {
            int idx = tid + i * 256, r = idx >> 5, c4 = idx & 31;
            size_t in_off = ((size_t)(b * 1024 + s0 + r) << 10) + (e << 7) + (c4 << 2);
            float4 q = *(const float4*)(Q + in_off);
            float4 k = *(const float4*)(K + in_off);
            size_t oo = plane + (((size_t)(s0 + r)) << 7) + (c4 << 2);
            *(ushort4*)(Qb + oo) = make_ushort4(f2bf(q.x), f2bf(q.y), f2bf(q.z), f2bf(q.w));
            *(ushort4*)(Kb + oo) = make_ushort4(f2bf(k.x), f2bf(k.y), f2bf(k.z), f2bf(k.w));
        }
    }
    if (av) {
        #pragma unroll
        for (int i = 0; i < 8; ++i) {
            int idx = tid + i * 256, r = idx >> 5, c4 = idx & 31;
            size_t in_off = ((size_t)(b * 1024 + s0 + r) << 10) + (e << 7) + (c4 << 2);
            float4 v = *(const float4*)(V + in_off);
            ushort_t* p = &tile[r][c4 << 2];
            p[0] = f2bf(v.x); p[1] = f2bf(v.y); p[2] = f2bf(v.z); p[3] = f2bf(v.w);
        }
        __syncthreads();
        #pragma unroll
        for (int i = 0; i < 4; ++i) {
            int item = tid + i * 256, d = item & 127, sg = item >> 7;
            union { uint4 q; ushort_t u[8]; } tmp;
            #pragma unroll
            for (int j = 0; j < 8; ++j) tmp.u[j] = tile[sg * 8 + j][d];
            *(uint4*)(Vt + plane + (((size_t)d) << 10) + s0 + (sg << 3)) = tmp.q;
        }
    }
}

// ---------------------------------------------------------------------------
// Kernel 2: lsums[b][e][s] = sum_t exp(scale*(Q_e K_e^T)[s][t]).
// Grid (16 stile64, 8 e, 4 b), exit if !em. Waves 2x2 over 64x64 chunk.
// Double-buffered 64-row K chunks, prefetch-BEFORE-compute (m97 order):
// one barrier per chunk; DMA drain overlaps compute.
// ---------------------------------------------------------------------------
__global__ __launch_bounds__(256, 2) void attn_pass1(
        const ushort_t* __restrict__ Qb, const ushort_t* __restrict__ Kb,
        const int* __restrict__ em, float* __restrict__ lsums) {

    __shared__ __align__(16) ushort_t qtile[64 * 128];
    __shared__ __align__(16) ushort_t ktile[2][64 * 128];
    __shared__ float red[2][64];

    const int stile = blockIdx.x, e = blockIdx.y, b = blockIdx.z;
    if (em[e * B_ + b] == 0) return;

    const int tid = threadIdx.x;
    const int w = tid >> 6, lane = tid & 63;
    const int quad = lane >> 4, l16 = lane & 15;
    const int wm = w & 1, wn = w >> 1;
    const int s0 = stile * 64;
    const size_t plane = ((size_t)(b * 8 + e)) << 17;

    stage64(Qb + plane + ((size_t)s0 << 7), 128, qtile, w, lane);
    stage64(Kb + plane, 128, ktile[0], w, lane);
    __syncthreads();

    short8 af[2][4];
    #pragma unroll
    for (int mi = 0; mi < 2; ++mi)
        #pragma unroll
        for (int kk = 0; kk < 4; ++kk)
            af[mi][kk] = fld(qtile, 32 * wm + 16 * mi + l16, (kk << 2) + quad);

    float rsum[2][4] = {{0.f,0.f,0.f,0.f},{0.f,0.f,0.f,0.f}};

    for (int tc = 0; tc < 16; ++tc) {
        if (tc < 15)
            stage64(Kb + plane + (((size_t)(tc + 1)) << 13), 128,
                    ktile[(tc + 1) & 1], w, lane);
        const ushort_t* kb = ktile[tc & 1];

        f32x4 sacc[2][2];
        #pragma unroll
        for (int mi = 0; mi < 2; ++mi)
            #pragma unroll
            for (int ni = 0; ni < 2; ++ni) sacc[mi][ni] = (f32x4){0.f,0.f,0.f,0.f};
        #pragma unroll
        for (int ni = 0; ni < 2; ++ni)
            #pragma unroll
            for (int kk = 0; kk < 4; ++kk) {
                short8 bf = fld(kb, 32 * wn + 16 * ni + l16, (kk << 2) + quad);
                #pragma unroll
                for (int mi = 0; mi < 2; ++mi)
                    sacc[mi][ni] = __builtin_amdgcn_mfma_f32_16x16x32_bf16(
                        af[mi][kk], bf, sacc[mi][ni], 0, 0, 0);
            }
        #pragma unroll
        for (int mi = 0; mi < 2; ++mi)
            #pragma unroll
            for (int ni = 0; ni < 2; ++ni)
                #pragma unroll
                for (int r = 0; r < 4; ++r)
                    rsum[mi][r] += __expf(sacc[mi][ni][r] * SCALE_);
        __syncthreads();
    }

    #pragma unroll
    for (int off = 1; off < 16; off <<= 1)
        #pragma unroll
        for (int mi = 0; mi < 2; ++mi)
            #pragma unroll
            for (int r = 0; r < 4; ++r)
                rsum[mi][r] += __shfl_xor(rsum[mi][r], off, 64);
    if (l16 == 0) {
        #pragma unroll
        for (int mi = 0; mi < 2; ++mi)
            #pragma unroll
            for (int r = 0; r < 4; ++r)
                red[wn][32 * wm + 16 * mi + quad * 4 + r] = rsum[mi][r];
    }
    __syncthreads();
    if (tid < 64)
        lsums[(((size_t)(b * 8 + e)) << 10) + s0 + tid] = red[0][tid] + red[1][tid];
}

// ---------------------------------------------------------------------------
// Kernel 3: attnB[b][s][t] = bf16( sum_e mask * exp(scale*QK)[s][t]/l_e[s] ).
// Grid (16 stile64, 16 ttile64, 4 b) = 1024 blocks. Expert loop double-
// buffered (packed active-expert list), prefetch-before-compute, one
// barrier per expert. 64 KB LDS -> 2 blocks/CU.
// ---------------------------------------------------------------------------
__global__ __launch_bounds__(256, 2) void attn_passC(
        const ushort_t* __restrict__ Qb, const ushort_t* __restrict__ Kb,
        const float* __restrict__ lsums, const int* __restrict__ em,
        ushort_t* __restrict__ attnB) {

    __shared__ __align__(16) ushort_t qtile[2][64 * 128];
    __shared__ __align__(16) ushort_t ktile[2][64 * 128];

    const int stile = blockIdx.x, tt = blockIdx.y, b = blockIdx.z;
    const int tid = threadIdx.x;
    const int w = tid >> 6, lane = tid & 63;
    const int quad = lane >> 4, l16 = lane & 15;
    const int wm = w & 1, wn = w >> 1;
    const int s0 = stile * 64, t0 = tt * 64;

    uint32 epack = 0; int ne = 0;
    #pragma unroll
    for (int e = 0; e < 8; ++e)
        if (em[e * B_ + b] != 0) { epack |= (uint32)e << (3 * ne); ++ne; }

    f32x4 aacc[2][2];
    #pragma unroll
    for (int mi = 0; mi < 2; ++mi)
        #pragma unroll
        for (int ni = 0; ni < 2; ++ni) aacc[mi][ni] = (f32x4){0.f,0.f,0.f,0.f};

    if (ne > 0) {
        {
            int e0 = epack & 7;
            size_t pl = ((size_t)(b * 8 + e0)) << 17;
            stage64(Qb + pl + ((size_t)s0 << 7), 128, qtile[0], w, lane);
            stage64(Kb + pl + ((size_t)t0 << 7), 128, ktile[0], w, lane);
        }
        __syncthreads();

        for (int i = 0; i < ne; ++i) {
            if (i + 1 < ne) {
                int en = (epack >> (3 * (i + 1))) & 7;
                size_t pl = ((size_t)(b * 8 + en)) << 17;
                stage64(Qb + pl + ((size_t)s0 << 7), 128, qtile[(i + 1) & 1], w, lane);
                stage64(Kb + pl + ((size_t)t0 << 7), 128, ktile[(i + 1) & 1], w, lane);
            }
            int e = (epack >> (3 * i)) & 7;
            float rinv[2][4];
            #pragma unroll
            for (int mi = 0; mi < 2; ++mi)
                #pragma unroll
                for (int r = 0; r < 4; ++r)
                    rinv[mi][r] = 1.0f / lsums[(((size_t)(b * 8 + e)) << 10)
                                               + s0 + 32 * wm + 16 * mi + quad * 4 + r];

            const ushort_t* qb = qtile[i & 1];
            const ushort_t* kb = ktile[i & 1];
            short8 af[2][4];
            #pragma unroll
            for (int mi = 0; mi < 2; ++mi)
                #pragma unroll
                for (int kk = 0; kk < 4; ++kk)
                    af[mi][kk] = fld(qb, 32 * wm + 16 * mi + l16, (kk << 2) + quad);

            f32x4 sacc[2][2];
            #pragma unroll
            for (int mi = 0; mi < 2; ++mi)
                #pragma unroll
                for (int ni = 0; ni < 2; ++ni) sacc[mi][ni] = (f32x4){0.f,0.f,0.f,0.f};
            #pragma unroll
            for (int ni = 0; ni < 2; ++ni)
                #pragma unroll
                for (int kk = 0; kk < 4; ++kk) {
                    short8 bf = fld(kb, 32 * wn + 16 * ni + l16, (kk << 2) + quad);
                    #pragma unroll
                    for (int mi = 0; mi < 2; ++mi)
                        sacc[mi][ni] = __builtin_amdgcn_mfma_f32_16x16x32_bf16(
                            af[mi][kk], bf, sacc[mi][ni], 0, 0, 0);
                }
            #pragma unroll
            for (int mi = 0; mi < 2; ++mi)
                #pragma unroll
                for (int ni = 0; ni < 2; ++ni)
                    #pragma unroll
                    for (int r = 0; r < 4; ++r)
                        aacc[mi][ni][r] += __expf(sacc[mi][ni][r] * SCALE_) * rinv[mi][r];
            __syncthreads();
        }
    }

    #pragma unroll
    for (int mi = 0; mi < 2; ++mi)
        #pragma unroll
        for (int ni = 0; ni < 2; ++ni)
            #pragma unroll
            for (int r = 0; r < 4; ++r)
                attnB[(((size_t)(b * 1024 + s0 + 32 * wm + 16 * mi + quad * 4 + r)) << 10)
                      + t0 + 32 * wn + 16 * ni + l16] = f2bf(aacc[mi][ni][r]);
}

// ---------------------------------------------------------------------------
// Kernel 4: out[b][s][e*128+d] = attn @ V_e if e in top2 else 0.
// Grid (16 stile64, 8 e, 4 b); double-buffered 128-t chunks,
// prefetch-before-compute, one barrier per chunk.
// ---------------------------------------------------------------------------
__global__ __launch_bounds__(256, 1) void attn_pass2(
        const ushort_t* __restrict__ Vt, const ushort_t* __restrict__ attnB,
        const float* __restrict__ route, float* __restrict__ out) {

    __shared__ __align__(16) ushort_t atile[2][64 * 128];
    __shared__ __align__(16) ushort_t vtile[2][128 * 128];

    const int stile = blockIdx.x, e = blockIdx.y, b = blockIdx.z;
    const int tid = threadIdx.x;
    const int w = tid >> 6, lane = tid & 63;
    const int quad = lane >> 4, l16 = lane & 15;
    const int wm = w & 1, wn = w >> 1;
    const int s0 = stile * 64;

    int i1, i2; top2(route + b * 8, i1, i2);

    if (e != i1 && e != i2) {
        #pragma unroll
        for (int i = 0; i < 8; ++i) {
            int idx = tid + i * 256, r = idx >> 5, c4 = idx & 31;
            *(float4*)(out + (((size_t)(b * 1024 + s0 + r)) << 10) + (e << 7) + (c4 << 2))
                = make_float4(0.f, 0.f, 0.f, 0.f);
        }
        return;
    }

    const size_t vplane = ((size_t)(b * 8 + e)) << 17;
    const ushort_t* abase = attnB + (((size_t)(b * 1024 + s0)) << 10);

    stage64(abase, 1024, atile[0], w, lane);
    stage128(Vt + vplane, 1024, vtile[0], w, lane);
    __syncthreads();

    f32x4 oacc[2][4];
    #pragma unroll
    for (int mi = 0; mi < 2; ++mi)
        #pragma unroll
        for (int ni = 0; ni < 4; ++ni) oacc[mi][ni] = (f32x4){0.f,0.f,0.f,0.f};

    for (int tc = 0; tc < 8; ++tc) {
        if (tc < 7) {
            stage64(abase + ((tc + 1) << 7), 1024, atile[(tc + 1) & 1], w, lane);
            stage128(Vt + vplane + ((tc + 1) << 7), 1024, vtile[(tc + 1) & 1], w, lane);
        }
        const ushort_t* at = atile[tc & 1];
        const ushort_t* vt = vtile[tc & 1];

        short8 af[2][4];
        #pragma unroll
        for (int mi = 0; mi < 2; ++mi)
            #pragma unroll
            for (int kk = 0; kk < 4; ++kk)
                af[mi][kk] = fld(at, 32 * wm + 16 * mi + l16, (kk << 2) + quad);
        #pragma unroll
        for (int ni = 0; ni < 4; ++ni)
            #pragma unroll
            for (int kk = 0; kk < 4; ++kk) {
                short8 bf = fld(vt, 64 * wn + 16 * ni + l16, (kk << 2) + quad);
                #pragma unroll
                for (int mi = 0; mi < 2; ++mi)
                    oacc[mi][ni] = __builtin_amdgcn_mfma_f32_16x16x32_bf16(
                        af[mi][kk], bf, oacc[mi][ni], 0, 0, 0);
            }
        __syncthreads();
    }

    #pragma unroll
    for (int mi = 0; mi < 2; ++mi)
        #pragma unroll
        for (int ni = 0; ni < 4; ++ni)
            #pragma unroll
            for (int r = 0; r < 4; ++r)
                out[(((size_t)(b * 1024 + s0 + 32 * wm + 16 * mi + quad * 4 + r)) << 10)
                    + (e << 7) + 64 * wn + 16 * ni + l16] = oacc[mi][ni][r];
}

// ---------------------------------------------------------------------------
extern "C" void kernel_launch(void* const* d_in, const int* in_sizes, int n_in,
                              void* d_out, int out_size, void* d_ws, size_t ws_size,
                              hipStream_t stream) {
    const float* Q     = (const float*)d_in[0];
    const float* K     = (const float*)d_in[1];
    const float* V     = (const float*)d_in[2];
    const float* route = (const float*)d_in[3];
    const int*   em    = (const int*)d_in[4];
    float* out = (float*)d_out;

    const size_t NB = (size_t)B_ * E_ * S_ * DE_;     // 4.19M elems
    ushort_t* Qb = (ushort_t*)d_ws;
    ushort_t* Kb = Qb + NB;
    ushort_t* Vt = Kb + NB;
    float*    lsums = (float*)(Vt + NB);              // [B][E][S]
    ushort_t* attnB = (ushort_t*)(lsums + (size_t)B_ * E_ * S_);  // [B][S][S] bf16

    dim3 gp(16, 8, 4);
    prep_kernel<<<gp, 256, 0, stream>>>(Q, K, V, route, em, Qb, Kb, Vt);
    dim3 g1(16, 8, 4);
    attn_pass1<<<g1, 256, 0, stream>>>(Qb, Kb, em, lsums);
    dim3 gc(16, 16, 4);
    attn_passC<<<gc, 256, 0, stream>>>(Qb, Kb, lsums, em, attnB);
    dim3 g2(16, 8, 4);
    attn_pass2<<<g2, 256, 0, stream>>>(Vt, attnB, route, out);
}